// Round 4
// baseline (120.787 us; speedup 1.0000x reference)
//
#include <hip/hip_runtime.h>

// ChamferDistance2D: B=8, N=M=8192, fp32, scalar output.
// cost = sum_b [ mean_i min_j d(i,j) + mean_j min_i d(i,j) ],  d = squared L2.
// Store min_j of (|q_j|^2 - 2 p_i . q_j); add |p_i|^2 back in reduce.
//
// R12 = R11 resubmit (R11 bench died to container failure with no compile or
// correctness evidence; source re-audited clean). Thesis unchanged:
// R10 proved partial is stall-bound, not VALU-bound (VALUBusy fell 110->72
// with the x0.625 inst cut, time unchanged; true busy ~35%): barrier-lockstep
// waves all burst 6 broadcast ds_read_b128 into the one per-CU LDS pipe at
// once -> queue-drain latency fully exposed; occupancy can't fix it (R8 28%
// vs R9 51%: identical). The q-side stream is wave-uniform -> move it to
// SGPRs: chamfer_prep SoA-izes both inputs (+precomputed |q|^2), partial
// reads it with uniform float4 loads (compiler scalarizes to s_load), and
// v_pk_fma_f32 consumes the SGPR pair directly ("s" asm constraint; legal:
// 1 SGPR src per VALU inst, z addend kept in VGPRs via 8 movs/group).
// No LDS, no __syncthreads -> waves desync, SMEM latency hides under math.
// Per pair: 1.5 pk/min3 + 0.125 mov = 1.625 insts -> 22 us VALU floor.
// S 32->16: partial buffer 16->8 MB, reduce min-depth halved.

#define BATCH 8
#define NPTS  8192
#define TPB   256
#define IPT   8
#define PPB   (TPB * IPT)            // 2048
#define TILES (NPTS / PPB)           // 4
#define S     16                     // j-splits
#define JCH   (NPTS / S)             // 512 j's per block
#define NARR  (2 * BATCH * NPTS)     // 131072 points per SoA component
#define PARTN (2 * BATCH * S * NPTS) // floats in partial buffer (8 MB)

__device__ inline float min3f(float a, float b, float c) {
    float d;
    asm("v_min3_f32 %0, %1, %2, %3" : "=v"(d) : "v"(a), "v"(b), "v"(c));
    return d;
}

// d = a * b + c  (packed 2xf32); b is wave-uniform and fed from an SGPR pair.
__device__ inline float2 pkfma_vsv(float2 a, float2 b, float2 c) {
    float2 d;
    asm("v_pk_fma_f32 %0, %1, %2, %3" : "=v"(d) : "v"(a), "s"(b), "v"(c));
    return d;
}

// grid.x = NARR / TPB = 512: SoA-ize both inputs + precompute |p|^2.
__global__ __launch_bounds__(TPB)
void chamfer_prep(const float* __restrict__ p1, const float* __restrict__ p2,
                  float* __restrict__ sx, float* __restrict__ sy,
                  float* __restrict__ sz) {
    int idx = blockIdx.x * TPB + threadIdx.x;     // [0, NARR)
    int arr = idx >> 16;                          // BATCH*NPTS = 65536
    int rem = idx & (BATCH * NPTS - 1);
    float2 v = ((const float2*)(arr ? p2 : p1))[rem];
    sx[idx] = v.x;
    sy[idx] = v.y;
    sz[idx] = fmaf(v.x, v.x, v.y * v.y);
}

// grid.x = 2 * BATCH * TILES * S = 1024
__global__ __launch_bounds__(TPB, 4)
void chamfer_partial(const float* __restrict__ p1, const float* __restrict__ p2,
                     const float* __restrict__ sx, const float* __restrict__ sy,
                     const float* __restrict__ sz,
                     float* __restrict__ partial /* [2][B][S][N] */) {
    int blk   = blockIdx.x;
    int split = blk & (S - 1);      blk >>= 4;
    int tile  = blk & (TILES - 1);  blk >>= 2;
    int b     = blk & (BATCH - 1);  blk >>= 3;
    int dir   = blk;

    const float2* a = (const float2*)(dir ? p2 : p1) + (size_t)b * NPTS;
    // q side: dir==0 reads p2's SoA (arr=1), dir==1 reads p1's (arr=0)
    int qoff = (1 - dir) * (BATCH * NPTS) + b * NPTS + split * JCH;
    const float4* qx4 = (const float4*)(sx + qoff);
    const float4* qy4 = (const float4*)(sy + qoff);
    const float4* qz4 = (const float4*)(sz + qoff);

    int t = threadIdx.x;
    int pt_base = tile * PPB;

    float2 xp2[IPT], yp2[IPT];
    float  m[IPT];
#pragma unroll
    for (int k = 0; k < IPT; ++k) {
        float2 v = a[pt_base + k * TPB + t];
        xp2[k] = make_float2(-2.0f * v.x, -2.0f * v.x);
        yp2[k] = make_float2(-2.0f * v.y, -2.0f * v.y);
        m[k]   = 3.0e38f;
    }

    // 8 j's per group, all q operands wave-uniform: 6 s_load_dwordx4 feed
    // the SGPR file; per k: 8 v_pk_fma_f32 (one SGPR src each) + 4 v_min3.
    for (int g = 0; g < JCH / 8; ++g) {
        float4 x03 = qx4[2 * g], x47 = qx4[2 * g + 1];
        float4 y03 = qy4[2 * g], y47 = qy4[2 * g + 1];
        float4 z03 = qz4[2 * g], z47 = qz4[2 * g + 1];
        float2 qx01 = make_float2(x03.x, x03.y), qx23 = make_float2(x03.z, x03.w);
        float2 qx45 = make_float2(x47.x, x47.y), qx67 = make_float2(x47.z, x47.w);
        float2 qy01 = make_float2(y03.x, y03.y), qy23 = make_float2(y03.z, y03.w);
        float2 qy45 = make_float2(y47.x, y47.y), qy67 = make_float2(y47.z, y47.w);
        // z addend must be a VGPR (1 SGPR src per VALU inst): 8 movs/group.
        float2 z01 = make_float2(z03.x, z03.y), z23 = make_float2(z03.z, z03.w);
        float2 z45 = make_float2(z47.x, z47.y), z67 = make_float2(z47.z, z47.w);
#pragma unroll
        for (int k = 0; k < IPT; ++k) {
            float2 a01 = pkfma_vsv(yp2[k], qy01, pkfma_vsv(xp2[k], qx01, z01));
            float2 a23 = pkfma_vsv(yp2[k], qy23, pkfma_vsv(xp2[k], qx23, z23));
            float2 a45 = pkfma_vsv(yp2[k], qy45, pkfma_vsv(xp2[k], qx45, z45));
            float2 a67 = pkfma_vsv(yp2[k], qy67, pkfma_vsv(xp2[k], qx67, z67));
            m[k] = min3f(m[k], a01.x, a01.y);
            m[k] = min3f(m[k], a23.x, a23.y);
            m[k] = min3f(m[k], a45.x, a45.y);
            m[k] = min3f(m[k], a67.x, a67.y);
        }
    }

    float* outp = partial + ((size_t)((dir * BATCH + b) * S + split)) * NPTS + pt_base;
#pragma unroll
    for (int k = 0; k < IPT; ++k)
        outp[k * TPB + t] = m[k];
}

// grid.x = 2 * BATCH * NPTS / TPB = 512.  No atomics: block sum -> bsum[bid].
__global__ __launch_bounds__(TPB)
void chamfer_reduce(const float* __restrict__ p1, const float* __restrict__ p2,
                    const float* __restrict__ partial, float* __restrict__ bsum) {
    int gid   = blockIdx.x * TPB + threadIdx.x;
    int point = gid & (NPTS - 1);
    int rest  = gid >> 13;
    int b     = rest & (BATCH - 1);
    int dir   = rest >> 3;

    const float* base = partial + ((size_t)(dir * BATCH + b) * S) * NPTS + point;
    float m = base[0];
#pragma unroll
    for (int s = 1; s < S; ++s)
        m = fminf(m, base[(size_t)s * NPTS]);

    float2 v = ((const float2*)(dir ? p2 : p1))[(size_t)b * NPTS + point];
    float d = m + fmaf(v.x, v.x, v.y * v.y);

#pragma unroll
    for (int off = 32; off > 0; off >>= 1)
        d += __shfl_down(d, off, 64);

    __shared__ float wsum[TPB / 64];
    int lane = threadIdx.x & 63;
    int w    = threadIdx.x >> 6;
    if (lane == 0) wsum[w] = d;
    __syncthreads();
    if (threadIdx.x == 0)
        bsum[blockIdx.x] = wsum[0] + wsum[1] + wsum[2] + wsum[3];
}

// grid.x = 1: sum 512 block sums, write the scalar. Deterministic, no atomics.
__global__ __launch_bounds__(TPB)
void chamfer_final(const float* __restrict__ bsum, float* __restrict__ out) {
    int t = threadIdx.x;
    float s = bsum[t] + bsum[t + TPB];

#pragma unroll
    for (int off = 32; off > 0; off >>= 1)
        s += __shfl_down(s, off, 64);

    __shared__ float wsum[TPB / 64];
    int lane = t & 63;
    int w    = t >> 6;
    if (lane == 0) wsum[w] = s;
    __syncthreads();
    if (t == 0)
        *out = (wsum[0] + wsum[1] + wsum[2] + wsum[3]) * (1.0f / NPTS);
}

extern "C" void kernel_launch(void* const* d_in, const int* in_sizes, int n_in,
                              void* d_out, int out_size, void* d_ws, size_t ws_size,
                              hipStream_t stream) {
    const float* p1 = (const float*)d_in[0];
    const float* p2 = (const float*)d_in[1];
    float* out      = (float*)d_out;
    float* partial  = (float*)d_ws;            // 8 MB
    float* bsum     = partial + PARTN;         // 2 KB (512 floats)
    float* sx       = bsum + 512;              // SoA: 3 x 512 KB, 16B-aligned
    float* sy       = sx + NARR;
    float* sz       = sy + NARR;

    chamfer_prep<<<NARR / TPB, TPB, 0, stream>>>(p1, p2, sx, sy, sz);
    chamfer_partial<<<2 * BATCH * TILES * S, TPB, 0, stream>>>(p1, p2, sx, sy, sz, partial);
    chamfer_reduce<<<2 * BATCH * NPTS / TPB, TPB, 0, stream>>>(p1, p2, partial, bsum);
    chamfer_final<<<1, TPB, 0, stream>>>(bsum, out);
}

// Round 6
// 119.439 us; speedup vs baseline: 1.0113x; 1.0113x over previous
//
#include <hip/hip_runtime.h>

// ChamferDistance2D: B=8, N=M=8192, fp32, scalar output.
// cost = sum_b [ mean_i min_j d(i,j) + mean_j min_i d(i,j) ],  d = squared L2.
// Store min_j of (|q_j|^2 - 2 p_i . q_j); add |p_i|^2 back in reduce.
//
// R14: pk_fma + IPT=16 combined. Serial LDS+VALU cycle model fits all
// history: R8 (IPT16, plain fma) = VALU 84k/SIMD + LDS 49k/CU -> 55us model,
// 64 measured; R10 (IPT8, pk) = VALU 54k + LDS 74k -> 53us model, 62
// measured. The plateau: R10's pk win was re-spent on LDS (IPT 16->8 doubled
// LDS bytes/pair). This round takes BOTH: per 8-j group 6 ds_read_b128 feed
// 16 k-iters x (8 pk_fma + 4 min3) = 8192 pairs -> LDS 37k cyc/CU (15us) +
// VALU 51k cyc/SIMD (21us), x1.17 calibration ~= 42us partial.
// R13's cooperative fusion FAILED correctness (stale cross-XCD reads at
// grid.sync) -> backend reverts to R10's proven reduce+final (S=32).
// xp/yp duplicated float2 (VOP3P f32 srcs are VGPR pairs; op_sel saves
// nothing): ~120 VGPR under the (256,4) 128-cap; compiler may park cold
// arrays in AGPRs (seen in R8, cheap).

#define BATCH 8
#define NPTS  8192
#define TPB   256
#define IPT   16
#define PPB   (TPB * IPT)            // 4096
#define TILES (NPTS / PPB)           // 2
#define S     32                     // j-splits
#define JCH   (NPTS / S)             // 256 j's per block
#define PARTN (2 * BATCH * S * NPTS) // floats in partial buffer (16 MB)

__device__ inline float min3f(float a, float b, float c) {
    float d;
    asm("v_min3_f32 %0, %1, %2, %3" : "=v"(d) : "v"(a), "v"(b), "v"(c));
    return d;
}

__device__ inline float2 pkfma(float2 a, float2 b, float2 c) {
    float2 d;
    asm("v_pk_fma_f32 %0, %1, %2, %3" : "=v"(d) : "v"(a), "v"(b), "v"(c));
    return d;
}

// grid.x = 2 * BATCH * TILES * S = 1024  (4 blocks/CU on 256 CUs)
__global__ __launch_bounds__(TPB, 4)
void chamfer_partial(const float* __restrict__ p1, const float* __restrict__ p2,
                     float* __restrict__ partial /* [2][B][S][N] */) {
    __shared__ __align__(16) float qx[JCH];
    __shared__ __align__(16) float qy[JCH];
    __shared__ __align__(16) float qz[JCH];

    int blk   = blockIdx.x;
    int split = blk & (S - 1);      blk >>= 5;
    int tile  = blk & (TILES - 1);  blk >>= 1;
    int b     = blk & (BATCH - 1);  blk >>= 3;
    int dir   = blk;

    const float2* a  = (const float2*)(dir ? p2 : p1) + (size_t)b * NPTS;
    const float2* bp = (const float2*)(dir ? p1 : p2) + (size_t)b * NPTS + split * JCH;

    int t = threadIdx.x;

    {   // JCH == TPB: one q-point per thread, SoA layout
        float2 v = bp[t];
        qx[t] = v.x;
        qy[t] = v.y;
        qz[t] = fmaf(v.x, v.x, v.y * v.y);
    }

    int pt_base = tile * PPB;
    float2 xp2[IPT], yp2[IPT];
    float  m[IPT];
#pragma unroll
    for (int k = 0; k < IPT; ++k) {
        float2 v = a[pt_base + k * TPB + t];
        xp2[k] = make_float2(-2.0f * v.x, -2.0f * v.x);
        yp2[k] = make_float2(-2.0f * v.y, -2.0f * v.y);
        m[k]   = 3.0e38f;
    }

    __syncthreads();

    // 8 j's per group: 6 broadcast ds_read_b128; per k: 8 pk_fma + 4 min3.
    // 8192 pairs per wave-group -> LDS ~1.5B/pair delivered, VALU 1.5/pair.
    for (int j = 0; j < JCH; j += 8) {
        float4 x03 = *(const float4*)&qx[j];
        float4 x47 = *(const float4*)&qx[j + 4];
        float4 y03 = *(const float4*)&qy[j];
        float4 y47 = *(const float4*)&qy[j + 4];
        float4 z03 = *(const float4*)&qz[j];
        float4 z47 = *(const float4*)&qz[j + 4];
        float2 x01 = make_float2(x03.x, x03.y), x23 = make_float2(x03.z, x03.w);
        float2 x45 = make_float2(x47.x, x47.y), x67 = make_float2(x47.z, x47.w);
        float2 y01 = make_float2(y03.x, y03.y), y23 = make_float2(y03.z, y03.w);
        float2 y45 = make_float2(y47.x, y47.y), y67 = make_float2(y47.z, y47.w);
        float2 z01 = make_float2(z03.x, z03.y), z23 = make_float2(z03.z, z03.w);
        float2 z45 = make_float2(z47.x, z47.y), z67 = make_float2(z47.z, z47.w);
#pragma unroll
        for (int k = 0; k < IPT; ++k) {
            float2 a01 = pkfma(yp2[k], y01, pkfma(xp2[k], x01, z01));
            float2 a23 = pkfma(yp2[k], y23, pkfma(xp2[k], x23, z23));
            float2 a45 = pkfma(yp2[k], y45, pkfma(xp2[k], x45, z45));
            float2 a67 = pkfma(yp2[k], y67, pkfma(xp2[k], x67, z67));
            m[k] = min3f(m[k], a01.x, a01.y);
            m[k] = min3f(m[k], a23.x, a23.y);
            m[k] = min3f(m[k], a45.x, a45.y);
            m[k] = min3f(m[k], a67.x, a67.y);
        }
    }

    float* outp = partial + ((size_t)((dir * BATCH + b) * S + split)) * NPTS + pt_base;
#pragma unroll
    for (int k = 0; k < IPT; ++k)
        outp[k * TPB + t] = m[k];
}

// grid.x = 2 * BATCH * NPTS / TPB = 512.  No atomics: block sum -> bsum[bid].
__global__ __launch_bounds__(TPB)
void chamfer_reduce(const float* __restrict__ p1, const float* __restrict__ p2,
                    const float* __restrict__ partial, float* __restrict__ bsum) {
    int gid   = blockIdx.x * TPB + threadIdx.x;
    int point = gid & (NPTS - 1);
    int rest  = gid >> 13;
    int b     = rest & (BATCH - 1);
    int dir   = rest >> 3;

    const float* base = partial + ((size_t)(dir * BATCH + b) * S) * NPTS + point;
    float m = base[0];
#pragma unroll
    for (int s = 1; s < S; ++s)
        m = fminf(m, base[(size_t)s * NPTS]);

    float2 v = ((const float2*)(dir ? p2 : p1))[(size_t)b * NPTS + point];
    float d = m + fmaf(v.x, v.x, v.y * v.y);

#pragma unroll
    for (int off = 32; off > 0; off >>= 1)
        d += __shfl_down(d, off, 64);

    __shared__ float wsum[TPB / 64];
    int lane = threadIdx.x & 63;
    int w    = threadIdx.x >> 6;
    if (lane == 0) wsum[w] = d;
    __syncthreads();
    if (threadIdx.x == 0)
        bsum[blockIdx.x] = wsum[0] + wsum[1] + wsum[2] + wsum[3];
}

// grid.x = 1: sum 512 block sums, write the scalar. Deterministic, no atomics.
__global__ __launch_bounds__(TPB)
void chamfer_final(const float* __restrict__ bsum, float* __restrict__ out) {
    int t = threadIdx.x;
    float s = bsum[t] + bsum[t + TPB];

#pragma unroll
    for (int off = 32; off > 0; off >>= 1)
        s += __shfl_down(s, off, 64);

    __shared__ float wsum[TPB / 64];
    int lane = t & 63;
    int w    = t >> 6;
    if (lane == 0) wsum[w] = s;
    __syncthreads();
    if (t == 0)
        *out = (wsum[0] + wsum[1] + wsum[2] + wsum[3]) * (1.0f / NPTS);
}

extern "C" void kernel_launch(void* const* d_in, const int* in_sizes, int n_in,
                              void* d_out, int out_size, void* d_ws, size_t ws_size,
                              hipStream_t stream) {
    const float* p1 = (const float*)d_in[0];
    const float* p2 = (const float*)d_in[1];
    float* out      = (float*)d_out;
    float* partial  = (float*)d_ws;            // 16 MB
    float* bsum     = partial + PARTN;         // 2 KB (512 floats)

    chamfer_partial<<<2 * BATCH * TILES * S, TPB, 0, stream>>>(p1, p2, partial);
    chamfer_reduce<<<2 * BATCH * NPTS / TPB, TPB, 0, stream>>>(p1, p2, partial, bsum);
    chamfer_final<<<1, TPB, 0, stream>>>(bsum, out);
}